// Round 4
// baseline (2010.331 us; speedup 1.0000x reference)
//
#include <hip/hip_runtime.h>
#include <stdint.h>

#define NN   2048
#define TTT  512
#define NT   (NN * TTT)          /* 1048576 rows */
#define NTM  (NN * (TTT - 1))    /* 1046528 rows */
#define SLOPE 0.01f
#define BN_EPS 1e-5f

typedef unsigned int uint;

/* ---- workspace layout ----
   bytes [0, 28KB)      : fp32 weights + affine (float offsets below)
   bytes [32768, 33792) : stats (192 edge + 64 node floats)
   bytes [36864, 36868) : dtype flag
   bytes [65536, ...)   : OPTIONAL edge branch outputs [3][NT][32] fp32 (402 MB)
                          used only when ws_size is large enough; otherwise we
                          fall back to recomputing the edge MLP in pass 2. */
#define W_EW1   0      /* [33][32] row-major, dir row at +1024 */
#define W_EW1C  1056   /* [16][32] combined (W1a+W1b) for inplace branch */
#define W_EB1   1568
#define W_EW2   1600   /* [32][32] */
#define W_EB2   2624
#define W_EW3   2656   /* [32][32] */
#define W_EB3   3680
#define W_NW1   3712   /* [32][32] */
#define W_NB1   4736
#define W_NW2   4768   /* [32][32] */
#define W_NB2   5792
#define W_NW3   5824   /* [32][32] */
#define W_NB3   6848
#define W_AFF   6880   /* [3][64]: per branch scale[32] then shift[32] */
#define W_TOTAL 7072

#define WS_EDGE_BYTE_OFF 65536ull
#define EOUT_BR_STRIDE   ((size_t)NT * 32u)   /* floats */

__device__ __forceinline__ float bf2f(uint16_t u) {
    union { uint u32; float f; } v; v.u32 = ((uint)u) << 16; return v.f;
}
__device__ __forceinline__ uint16_t f2bf(float f) {
    union { float f; uint u; } v; v.f = f;
    uint r = v.u + 0x7FFFu + ((v.u >> 16) & 1u);   // RTNE
    return (uint16_t)(r >> 16);
}

template <bool F32>
__device__ __forceinline__ float wv(const void* W, int i) {
    return F32 ? ((const float*)W)[i] : bf2f(((const uint16_t*)W)[i]);
}

template <bool F32>
__device__ __forceinline__ void loadrow16(const void* x, size_t elt, float* f) {
    if (F32) {
        const float4* q = (const float4*)((const float*)x + elt);
        float4 a = q[0], b = q[1], c = q[2], d = q[3];
        f[0]=a.x; f[1]=a.y; f[2]=a.z; f[3]=a.w;
        f[4]=b.x; f[5]=b.y; f[6]=b.z; f[7]=b.w;
        f[8]=c.x; f[9]=c.y; f[10]=c.z; f[11]=c.w;
        f[12]=d.x; f[13]=d.y; f[14]=d.z; f[15]=d.w;
    } else {
        const uint4* q = (const uint4*)((const uint16_t*)x + elt);
        uint4 a = q[0], b = q[1];
        uint w[8] = {a.x, a.y, a.z, a.w, b.x, b.y, b.z, b.w};
#pragma unroll
        for (int i = 0; i < 8; i++) {
            union { uint u; float f; } lo, hi;
            lo.u = w[i] << 16; hi.u = w[i] & 0xFFFF0000u;
            f[2*i] = lo.f; f[2*i+1] = hi.f;
        }
    }
}
template <bool F32>
__device__ __forceinline__ void loadrow32(const void* x, size_t elt, float* f) {
    loadrow16<F32>(x, elt, f); loadrow16<F32>(x, elt + 16, f + 16);
}
template <bool F32>
__device__ __forceinline__ void storerow32(void* out, size_t elt, const float* f) {
    if (F32) {
        float4* q = (float4*)((float*)out + elt);
#pragma unroll
        for (int i = 0; i < 8; i++)
            q[i] = make_float4(f[4*i], f[4*i+1], f[4*i+2], f[4*i+3]);
    } else {
        uint w[16];
#pragma unroll
        for (int i = 0; i < 16; i++)
            w[i] = (uint)f2bf(f[2*i]) | ((uint)f2bf(f[2*i+1]) << 16);
        uint4* q = (uint4*)((uint16_t*)out + elt);
        q[0] = make_uint4(w[0], w[1], w[2], w[3]);
        q[1] = make_uint4(w[4], w[5], w[6], w[7]);
        q[2] = make_uint4(w[8], w[9], w[10], w[11]);
        q[3] = make_uint4(w[12], w[13], w[14], w[15]);
    }
}

// h[j] += sum_i W[i*32+j] * in[i].  W is a wave-uniform global fp32 pointer:
// uniform address + __restrict__ => s_load (SMEM), weights live in SGPRs,
// v_fmac reads 1 SGPR + 2 VGPRs.
template <int K>
__device__ __forceinline__ void dense(const float* __restrict__ W, const float* in, float* h) {
#pragma unroll 2
    for (int i = 0; i < K; i++) {
        const float x = in[i];
        const float4* __restrict__ w4 = (const float4*)(W + i * 32);
#pragma unroll
        for (int j = 0; j < 8; j++) {
            float4 w = w4[j];
            h[4*j+0] = fmaf(w.x, x, h[4*j+0]);
            h[4*j+1] = fmaf(w.y, x, h[4*j+1]);
            h[4*j+2] = fmaf(w.z, x, h[4*j+2]);
            h[4*j+3] = fmaf(w.w, x, h[4*j+3]);
        }
    }
}
__device__ __forceinline__ void lrelu32(float* h) {
#pragma unroll
    for (int j = 0; j < 32; j++) h[j] = fmaxf(h[j], h[j] * SLOPE);
}

// full edge 3-layer MLP; dir: 0 (inplace, uses combined W1c), +1 fwd, -1 bwd
template <bool INPLACE>
__device__ __forceinline__ void edge_mlp(
    const float* __restrict__ W1, const float* __restrict__ W1c,
    const float* __restrict__ W2, const float* __restrict__ W3,
    const float* __restrict__ B1, const float* __restrict__ B2, const float* __restrict__ B3,
    const float* xt, const float* xn, float dir, float* o)
{
    float h1[32];
#pragma unroll
    for (int j = 0; j < 32; j++) h1[j] = fmaf(dir, W1[1024 + j], B1[j]);
    if (INPLACE) {
        dense<16>(W1c, xt, h1);
    } else {
        dense<16>(W1, xt, h1);
        dense<16>(W1 + 512, xn, h1);
    }
    lrelu32(h1);
    float h2[32];
#pragma unroll
    for (int j = 0; j < 32; j++) h2[j] = B2[j];
    dense<32>(W2, h1, h2);
    lrelu32(h2);
#pragma unroll
    for (int j = 0; j < 32; j++) o[j] = B3[j];
    dense<32>(W3, h2, o);
}

// Packed in-place reduce-scatter butterfly: sums v[j] and v[j]^2 over 64 lanes.
// DESTROYS v. lane L<32 -> sum of channel L; lane L>=32 -> sumsq of channel L-32.
// 63 shuffles total, zero extra registers. Proven correct in R2/R3 runs.
__device__ __forceinline__ float stats_reduce64(float* v, int lane) {
    const bool hi = lane >= 32;
#pragma unroll
    for (int j = 0; j < 32; j++) {
        float s = v[j], q = v[j] * v[j];
        float r = __shfl_xor(hi ? s : q, 32, 64);
        v[j] = (hi ? q : s) + r;
    }
#pragma unroll
    for (int m = 16; m >= 1; m >>= 1) {
        const bool b = (lane & m) != 0;
#pragma unroll
        for (int j = 0; j < m; j++) {
            float r = __shfl_xor(b ? v[j] : v[j + m], m, 64);
            v[j] = (b ? v[j + m] : v[j]) + r;
        }
    }
    return v[0];
}

// ---------------- prep: dtype detect + fp32 weight conversion ----------------
__global__ void prep_kernel(
    const uint* __restrict__ x,
    const void* __restrict__ eW1, const void* __restrict__ eb1,
    const void* __restrict__ eW2, const void* __restrict__ eb2,
    const void* __restrict__ eW3, const void* __restrict__ eb3,
    const void* __restrict__ nW1, const void* __restrict__ nb1,
    const void* __restrict__ nW2, const void* __restrict__ nb2,
    const void* __restrict__ nW3, const void* __restrict__ nb3,
    int* __restrict__ flag, float* __restrict__ wts)
{
    __shared__ int cnt;
    const int tid = threadIdx.x;
    if (tid == 0) cnt = 0;
    __syncthreads();
    if (tid < 64) {
        uint w = x[tid];
        uint e = (w >> 7) & 0xFFu;
        if (e >= 110u && e <= 134u) atomicAdd(&cnt, 1);
    }
    __syncthreads();
    const bool f32 = (cnt < 32);
    if (tid == 0) flag[0] = f32 ? 1 : 0;
    auto rd = [&](const void* p, int i) -> float {
        return f32 ? ((const float*)p)[i] : bf2f(((const uint16_t*)p)[i]);
    };
    for (int i = tid; i < 1056; i += 256) wts[W_EW1 + i] = rd(eW1, i);
    for (int i = tid; i < 512;  i += 256) wts[W_EW1C + i] = rd(eW1, i) + rd(eW1, 512 + i);
    for (int i = tid; i < 1024; i += 256) {
        wts[W_EW2 + i] = rd(eW2, i); wts[W_EW3 + i] = rd(eW3, i);
        wts[W_NW1 + i] = rd(nW1, i); wts[W_NW2 + i] = rd(nW2, i); wts[W_NW3 + i] = rd(nW3, i);
    }
    if (tid < 32) {
        wts[W_EB1 + tid] = rd(eb1, tid); wts[W_EB2 + tid] = rd(eb2, tid); wts[W_EB3 + tid] = rd(eb3, tid);
        wts[W_NB1 + tid] = rd(nb1, tid); wts[W_NB2 + tid] = rd(nb2, tid); wts[W_NB3 + tid] = rd(nb3, tid);
    }
}

// -------- pass 1 (stored variant): edge MLP x3, store outputs + stats --------
// STORE=true writes branch outputs to eout[3][NT][32] fp32.
template <bool F32, bool STORE>
__global__ __launch_bounds__(256, 2) void edge_pass_kernel(
    const void* __restrict__ x, const float* __restrict__ wts,
    const int* __restrict__ flag, float* __restrict__ gstats /*192*/,
    float* __restrict__ eout)
{
    if ((flag[0] != 0) != F32) return;
    __shared__ float sSt[192];
    const int tid = threadIdx.x;
    const int lane = tid & 63;
    if (tid < 192) sSt[tid] = 0.f;
    __syncthreads();

    const float* __restrict__ W1  = wts + W_EW1;
    const float* __restrict__ W1c = wts + W_EW1C;
    const float* __restrict__ W2  = wts + W_EW2;
    const float* __restrict__ W3  = wts + W_EW3;
    const float* __restrict__ B1  = wts + W_EB1;
    const float* __restrict__ B2  = wts + W_EB2;
    const float* __restrict__ B3  = wts + W_EB3;

    const uint r = blockIdx.x * 256u + (uint)tid;   // grid covers NT exactly
    const uint t = r & 511u;
    float xt[16]; loadrow16<F32>(x, (size_t)r << 4, xt);
    float o[32];

    // inplace
    edge_mlp<true>(W1, W1c, W2, W3, B1, B2, B3, xt, xt, 0.f, o);
    if (STORE) storerow32<true>((void*)eout, (size_t)r * 32u, o);
    atomicAdd(&sSt[lane], stats_reduce64(o, lane));

    // fwd: neighbor t-1, valid t>0 (store unmasked; mask only for stats)
    {
        const float vf = (t > 0u) ? 1.f : 0.f;
        const uint rn = (t > 0u) ? r - 1u : r;
        float xn[16]; loadrow16<F32>(x, (size_t)rn << 4, xn);
        edge_mlp<false>(W1, W1c, W2, W3, B1, B2, B3, xt, xn, 1.f, o);
        if (STORE) storerow32<true>((void*)eout, EOUT_BR_STRIDE + (size_t)r * 32u, o);
#pragma unroll
        for (int j = 0; j < 32; j++) o[j] *= vf;
        atomicAdd(&sSt[64 + lane], stats_reduce64(o, lane));
    }
    // bwd: neighbor t+1, valid t<511
    {
        const float vf = (t < 511u) ? 1.f : 0.f;
        const uint rn = (t < 511u) ? r + 1u : r;
        float xn[16]; loadrow16<F32>(x, (size_t)rn << 4, xn);
        edge_mlp<false>(W1, W1c, W2, W3, B1, B2, B3, xt, xn, -1.f, o);
        if (STORE) storerow32<true>((void*)eout, 2u * EOUT_BR_STRIDE + (size_t)r * 32u, o);
#pragma unroll
        for (int j = 0; j < 32; j++) o[j] *= vf;
        atomicAdd(&sSt[128 + lane], stats_reduce64(o, lane));
    }
    __syncthreads();
    if (tid < 192) atomicAdd(&gstats[tid], sSt[tid]);
}

// ------------- tiny: edge BN affine coefficients -> workspace (SGPR path) -------------
template <bool F32>
__global__ void edge_affine_kernel(
    const float* __restrict__ gstats_edge,
    const void* __restrict__ egamma, const void* __restrict__ ebeta,
    const int* __restrict__ flag, float* __restrict__ wts_aff)
{
    if ((flag[0] != 0) != F32) return;
    const int tid = threadIdx.x;
    if (tid < 32) {
        float g = wv<F32>(egamma, tid), be = wv<F32>(ebeta, tid);
#pragma unroll
        for (int br = 0; br < 3; br++) {
            float cnt = (br == 0) ? (float)NT : (float)NTM;
            float s = gstats_edge[br * 64 + tid], q = gstats_edge[br * 64 + 32 + tid];
            float mu = s / cnt;
            float var = q / cnt - mu * mu;
            float sc = g * rsqrtf(var + BN_EPS);
            wts_aff[W_AFF + br * 64 + tid] = sc;
            wts_aff[W_AFF + br * 64 + 32 + tid] = be - mu * sc;
        }
    }
}

// -------- pass 2 (stored variant): load branch outputs, affine, node MLP --------
template <bool F32>
__global__ __launch_bounds__(256, 2) void node_store_kernel(
    const float* __restrict__ eout, const float* __restrict__ wts,
    const int* __restrict__ flag, float* __restrict__ gstats_node,
    void* __restrict__ out)
{
    if ((flag[0] != 0) != F32) return;
    __shared__ float sSt[64];
    const int tid = threadIdx.x;
    const int lane = tid & 63;
    if (tid < 64) sSt[tid] = 0.f;
    __syncthreads();

    const float* __restrict__ AFF = wts + W_AFF;

    const uint r = blockIdx.x * 256u + (uint)tid;
    const uint t = r & 511u;
    const float vf0 = (t > 0u) ? 1.f : 0.f;
    const float vf1 = (t < 511u) ? 1.f : 0.f;

    float agg[32], o[32];
    loadrow32<true>((const void*)eout, (size_t)r * 32u, o);
#pragma unroll
    for (int j = 0; j < 32; j++) agg[j] = fmaf(AFF[j], o[j], AFF[32 + j]);
    loadrow32<true>((const void*)eout, EOUT_BR_STRIDE + (size_t)r * 32u, o);
#pragma unroll
    for (int j = 0; j < 32; j++) agg[j] += vf0 * fmaf(AFF[64 + j], o[j], AFF[96 + j]);
    loadrow32<true>((const void*)eout, 2u * EOUT_BR_STRIDE + (size_t)r * 32u, o);
#pragma unroll
    for (int j = 0; j < 32; j++) agg[j] += vf1 * fmaf(AFF[128 + j], o[j], AFF[160 + j]);

    const float* __restrict__ NW1 = wts + W_NW1;
    const float* __restrict__ NW2 = wts + W_NW2;
    const float* __restrict__ NW3 = wts + W_NW3;
    const float* __restrict__ NB1 = wts + W_NB1;
    const float* __restrict__ NB2 = wts + W_NB2;
    const float* __restrict__ NB3 = wts + W_NB3;

    float g1[32];
#pragma unroll
    for (int j = 0; j < 32; j++) g1[j] = NB1[j];
    dense<32>(NW1, agg, g1);
    lrelu32(g1);
    float g2[32];
#pragma unroll
    for (int j = 0; j < 32; j++) g2[j] = NB2[j];
    dense<32>(NW2, g1, g2);
    lrelu32(g2);
    float g3[32];
#pragma unroll
    for (int j = 0; j < 32; j++) g3[j] = NB3[j];
    dense<32>(NW3, g2, g3);

    storerow32<F32>(out, (size_t)r * 32u, g3);
    atomicAdd(&sSt[lane], stats_reduce64(g3, lane));
    __syncthreads();
    if (tid < 64) atomicAdd(&gstats_node[tid], sSt[tid]);
}

// -------- pass 2 (fallback): recompute edge MLP, affine, node MLP --------
template <bool F32>
__global__ __launch_bounds__(256, 2) void node_recompute_kernel(
    const void* __restrict__ x, const float* __restrict__ wts,
    const int* __restrict__ flag, float* __restrict__ gstats_node,
    void* __restrict__ out)
{
    if ((flag[0] != 0) != F32) return;
    __shared__ float sSt[64];
    const int tid = threadIdx.x;
    const int lane = tid & 63;
    if (tid < 64) sSt[tid] = 0.f;
    __syncthreads();

    const float* __restrict__ EW1  = wts + W_EW1;
    const float* __restrict__ EW1c = wts + W_EW1C;
    const float* __restrict__ EW2  = wts + W_EW2;
    const float* __restrict__ EW3  = wts + W_EW3;
    const float* __restrict__ EB1  = wts + W_EB1;
    const float* __restrict__ EB2  = wts + W_EB2;
    const float* __restrict__ EB3  = wts + W_EB3;
    const float* __restrict__ AFF  = wts + W_AFF;

    const uint r = blockIdx.x * 256u + (uint)tid;
    const uint t = r & 511u;
    float xt[16]; loadrow16<F32>(x, (size_t)r << 4, xt);
    float agg[32], o[32];

    edge_mlp<true>(EW1, EW1c, EW2, EW3, EB1, EB2, EB3, xt, xt, 0.f, o);
#pragma unroll
    for (int j = 0; j < 32; j++) agg[j] = fmaf(AFF[j], o[j], AFF[32 + j]);
    {
        const float vf = (t > 0u) ? 1.f : 0.f;
        const uint rn = (t > 0u) ? r - 1u : r;
        float xn[16]; loadrow16<F32>(x, (size_t)rn << 4, xn);
        edge_mlp<false>(EW1, EW1c, EW2, EW3, EB1, EB2, EB3, xt, xn, 1.f, o);
#pragma unroll
        for (int j = 0; j < 32; j++) agg[j] += vf * fmaf(AFF[64 + j], o[j], AFF[96 + j]);
    }
    {
        const float vf = (t < 511u) ? 1.f : 0.f;
        const uint rn = (t < 511u) ? r + 1u : r;
        float xn[16]; loadrow16<F32>(x, (size_t)rn << 4, xn);
        edge_mlp<false>(EW1, EW1c, EW2, EW3, EB1, EB2, EB3, xt, xn, -1.f, o);
#pragma unroll
        for (int j = 0; j < 32; j++) agg[j] += vf * fmaf(AFF[128 + j], o[j], AFF[160 + j]);
    }

    const float* __restrict__ NW1 = wts + W_NW1;
    const float* __restrict__ NW2 = wts + W_NW2;
    const float* __restrict__ NW3 = wts + W_NW3;
    const float* __restrict__ NB1 = wts + W_NB1;
    const float* __restrict__ NB2 = wts + W_NB2;
    const float* __restrict__ NB3 = wts + W_NB3;

    float g1[32];
#pragma unroll
    for (int j = 0; j < 32; j++) g1[j] = NB1[j];
    dense<32>(NW1, agg, g1);
    lrelu32(g1);
    float g2[32];
#pragma unroll
    for (int j = 0; j < 32; j++) g2[j] = NB2[j];
    dense<32>(NW2, g1, g2);
    lrelu32(g2);
    float g3[32];
#pragma unroll
    for (int j = 0; j < 32; j++) g3[j] = NB3[j];
    dense<32>(NW3, g2, g3);

    storerow32<F32>(out, (size_t)r * 32u, g3);
    atomicAdd(&sSt[lane], stats_reduce64(g3, lane));
    __syncthreads();
    if (tid < 64) atomicAdd(&gstats_node[tid], sSt[tid]);
}

// ---------------- pass 3: in-place node BN affine ----------------
template <bool F32>
__global__ __launch_bounds__(256) void finalize_kernel(
    const float* __restrict__ gstats_node,
    const void* __restrict__ ngamma, const void* __restrict__ nbeta,
    const int* __restrict__ flag, void* __restrict__ out)
{
    if ((flag[0] != 0) != F32) return;
    __shared__ float sc[32], sh[32];
    const int tid = threadIdx.x;
    if (tid < 32) {
        float s = gstats_node[tid], q = gstats_node[32 + tid];
        float mu = s / (float)NT;
        float var = q / (float)NT - mu * mu;
        float k = wv<F32>(ngamma, tid) * rsqrtf(var + BN_EPS);
        sc[tid] = k; sh[tid] = wv<F32>(nbeta, tid) - mu * k;
    }
    __syncthreads();
    const uint r = blockIdx.x * 256u + (uint)tid;
    float v[32]; loadrow32<F32>(out, (size_t)r * 32u, v);
    float o[32];
#pragma unroll
    for (int j = 0; j < 32; j++) o[j] = fmaf(sc[j], v[j], sh[j]);
    storerow32<F32>(out, (size_t)r * 32u, o);
}

extern "C" void kernel_launch(void* const* d_in, const int* in_sizes, int n_in,
                              void* d_out, int out_size, void* d_ws, size_t ws_size,
                              hipStream_t stream) {
    const void* x   = d_in[0];
    const void* eW1 = d_in[1]; const void* eb1 = d_in[2];
    const void* eW2 = d_in[3]; const void* eb2 = d_in[4];
    const void* eW3 = d_in[5]; const void* eb3 = d_in[6];
    const void* eg  = d_in[7]; const void* ebt = d_in[8];
    const void* nW1 = d_in[9]; const void* nb1 = d_in[10];
    const void* nW2 = d_in[11]; const void* nb2 = d_in[12];
    const void* nW3 = d_in[13]; const void* nb3 = d_in[14];
    const void* ng  = d_in[15]; const void* nbt = d_in[16];

    float* wts   = (float*)d_ws;                       // fp32 weights + affine, ~28 KB
    float* stats = (float*)((char*)d_ws + 32768);      // [0..191] edge, [192..255] node
    int* flag    = (int*)((char*)d_ws + 36864);        // dtype flag: 1 = fp32, 0 = bf16
    float* eout  = (float*)((char*)d_ws + WS_EDGE_BYTE_OFF);

    const size_t need = WS_EDGE_BYTE_OFF + 3ull * (size_t)NT * 32ull * sizeof(float);
    const bool stored = (ws_size >= need);

    hipMemsetAsync((char*)d_ws + 32768, 0, 8192, stream);
    prep_kernel<<<dim3(1), dim3(256), 0, stream>>>((const uint*)x,
        eW1, eb1, eW2, eb2, eW3, eb3, nW1, nb1, nW2, nb2, nW3, nb3, flag, wts);

    dim3 blk(256), grid(NT / 256);
    if (stored) {
        edge_pass_kernel<true,  true><<<grid, blk, 0, stream>>>(x, wts, flag, stats, eout);
        edge_pass_kernel<false, true><<<grid, blk, 0, stream>>>(x, wts, flag, stats, eout);
    } else {
        edge_pass_kernel<true,  false><<<grid, blk, 0, stream>>>(x, wts, flag, stats, eout);
        edge_pass_kernel<false, false><<<grid, blk, 0, stream>>>(x, wts, flag, stats, eout);
    }
    edge_affine_kernel<true><<<dim3(1), dim3(64), 0, stream>>>(stats, eg, ebt, flag, wts);
    edge_affine_kernel<false><<<dim3(1), dim3(64), 0, stream>>>(stats, eg, ebt, flag, wts);
    if (stored) {
        node_store_kernel<true><<<grid, blk, 0, stream>>>(eout, wts, flag, stats + 192, d_out);
        node_store_kernel<false><<<grid, blk, 0, stream>>>(eout, wts, flag, stats + 192, d_out);
    } else {
        node_recompute_kernel<true><<<grid, blk, 0, stream>>>(x, wts, flag, stats + 192, d_out);
        node_recompute_kernel<false><<<grid, blk, 0, stream>>>(x, wts, flag, stats + 192, d_out);
    }
    finalize_kernel<true><<<grid, blk, 0, stream>>>(stats + 192, ng, nbt, flag, d_out);
    finalize_kernel<false><<<grid, blk, 0, stream>>>(stats + 192, ng, nbt, flag, d_out);
}

// Round 5
// 951.879 us; speedup vs baseline: 2.1120x; 2.1120x over previous
//
#include <hip/hip_runtime.h>
#include <stdint.h>

#define NN   2048
#define TTT  512
#define NT   (NN * TTT)          /* 1048576 rows */
#define NTM  (NN * (TTT - 1))    /* 1046528 rows */
#define SLOPE 0.01f
#define BN_EPS 1e-5f

typedef unsigned int uint;
typedef float v2f __attribute__((ext_vector_type(2)));

/* ---- workspace layout ----
   bytes [0, 28KB)      : fp32 weights + affine (float offsets below)
   bytes [32768, 33792) : stats (192 edge + 64 node floats)
   bytes [36864, 36868) : dtype flag
   bytes [65536, ...)   : edge branch outputs [3][NT][32] fp32 (402 MB) when
                          ws_size permits; else recompute fallback. */
#define W_EW1   0      /* [33][32] row-major: W1a[16][32], W1b[16][32], dir row */
#define W_EB1   1568
#define W_EW2   1600   /* [32][32] */
#define W_EB2   2624
#define W_EW3   2656   /* [32][32] */
#define W_EB3   3680
#define W_NW1   3712   /* [32][32] */
#define W_NB1   4736
#define W_NW2   4768   /* [32][32] */
#define W_NB2   5792
#define W_NW3   5824   /* [32][32] */
#define W_NB3   6848
#define W_AFF   6880   /* [3][64]: per branch scale[32] then shift[32] */

#define WS_EDGE_BYTE_OFF 65536ull
#define EOUT_BR_STRIDE   ((size_t)NT * 32u)   /* floats */

__device__ __forceinline__ float bf2f(uint16_t u) {
    union { uint u32; float f; } v; v.u32 = ((uint)u) << 16; return v.f;
}
__device__ __forceinline__ uint16_t f2bf(float f) {
    union { float f; uint u; } v; v.f = f;
    uint r = v.u + 0x7FFFu + ((v.u >> 16) & 1u);   // RTNE
    return (uint16_t)(r >> 16);
}

template <bool F32>
__device__ __forceinline__ float wv(const void* W, int i) {
    return F32 ? ((const float*)W)[i] : bf2f(((const uint16_t*)W)[i]);
}

template <bool F32>
__device__ __forceinline__ void loadrow16(const void* x, size_t elt, float* f) {
    if (F32) {
        const float4* q = (const float4*)((const float*)x + elt);
        float4 a = q[0], b = q[1], c = q[2], d = q[3];
        f[0]=a.x; f[1]=a.y; f[2]=a.z; f[3]=a.w;
        f[4]=b.x; f[5]=b.y; f[6]=b.z; f[7]=b.w;
        f[8]=c.x; f[9]=c.y; f[10]=c.z; f[11]=c.w;
        f[12]=d.x; f[13]=d.y; f[14]=d.z; f[15]=d.w;
    } else {
        const uint4* q = (const uint4*)((const uint16_t*)x + elt);
        uint4 a = q[0], b = q[1];
        uint w[8] = {a.x, a.y, a.z, a.w, b.x, b.y, b.z, b.w};
#pragma unroll
        for (int i = 0; i < 8; i++) {
            union { uint u; float f; } lo, hi;
            lo.u = w[i] << 16; hi.u = w[i] & 0xFFFF0000u;
            f[2*i] = lo.f; f[2*i+1] = hi.f;
        }
    }
}
template <bool F32>
__device__ __forceinline__ void loadrow32(const void* x, size_t elt, float* f) {
    loadrow16<F32>(x, elt, f); loadrow16<F32>(x, elt + 16, f + 16);
}
template <bool F32>
__device__ __forceinline__ void storerow32(void* out, size_t elt, const float* f) {
    if (F32) {
        float4* q = (float4*)((float*)out + elt);
#pragma unroll
        for (int i = 0; i < 8; i++)
            q[i] = make_float4(f[4*i], f[4*i+1], f[4*i+2], f[4*i+3]);
    } else {
        uint w[16];
#pragma unroll
        for (int i = 0; i < 16; i++)
            w[i] = (uint)f2bf(f[2*i]) | ((uint)f2bf(f[2*i+1]) << 16);
        uint4* q = (uint4*)((uint16_t*)out + elt);
        q[0] = make_uint4(w[0], w[1], w[2], w[3]);
        q[1] = make_uint4(w[4], w[5], w[6], w[7]);
        q[2] = make_uint4(w[8], w[9], w[10], w[11]);
        q[3] = make_uint4(w[12], w[13], w[14], w[15]);
    }
}

// h[j] (v2f pair j = channels 2j,2j+1) += W[i][2j..] * in[i].
// Weights via wave-uniform s_load; accum as <2 x float> so ffp-contract can
// form v_pk_fma_f32 (dual fp32 FMA). If packing doesn't fire this degrades
// to the proven scalar v_fmac form -- no downside.
template <int K>
__device__ __forceinline__ void densev(const float* __restrict__ W, const float* in, v2f* h) {
#pragma unroll 2
    for (int i = 0; i < K; i++) {
        const float xi = in[i];
        const v2f* __restrict__ w2 = (const v2f*)(W + i * 32);
#pragma unroll
        for (int j = 0; j < 16; j++) h[j] += w2[j] * xi;
    }
}
template <int K>
__device__ __forceinline__ void densevv(const float* __restrict__ W, const v2f* in, v2f* h) {
#pragma unroll 2
    for (int i = 0; i < K; i++) {
        const float xi = in[i >> 1][i & 1];
        const v2f* __restrict__ w2 = (const v2f*)(W + i * 32);
#pragma unroll
        for (int j = 0; j < 16; j++) h[j] += w2[j] * xi;
    }
}
__device__ __forceinline__ void lrelu16v(v2f* h) {
#pragma unroll
    for (int j = 0; j < 16; j++) {
        v2f s = h[j] * SLOPE;
        v2f a = h[j];
        a[0] = fmaxf(a[0], s[0]);
        a[1] = fmaxf(a[1], s[1]);
        h[j] = a;
    }
}

// One edge branch, 3-layer MLP. o[16] v2f out.
__device__ __forceinline__ void edge_branch_compute(
    const float* __restrict__ wts, const void* __restrict__ x,
    uint r, uint rn, float dir, bool F32v, v2f* o)
{
    // (kept monomorphic on dtype via caller template; see wrappers below)
    (void)F32v; (void)x; (void)r; (void)rn; (void)dir; (void)wts; (void)o;
}

template <bool F32>
__device__ __forceinline__ void edge_mlp_v2f(
    const float* __restrict__ wts,
    const float* xt, const float* xn, float dir, v2f* o)
{
    const float* __restrict__ W1a = wts + W_EW1;
    const float* __restrict__ W1b = wts + W_EW1 + 512;
    const v2f* __restrict__ WDv = (const v2f*)(wts + W_EW1 + 1024);
    const v2f* __restrict__ B1v = (const v2f*)(wts + W_EB1);
    const float* __restrict__ W2 = wts + W_EW2;
    const v2f* __restrict__ B2v = (const v2f*)(wts + W_EB2);
    const float* __restrict__ W3 = wts + W_EW3;
    const v2f* __restrict__ B3v = (const v2f*)(wts + W_EB3);

    v2f h1[16];
#pragma unroll
    for (int k = 0; k < 16; k++) h1[k] = B1v[k] + WDv[k] * dir;
    densev<16>(W1a, xt, h1);
    densev<16>(W1b, xn, h1);
    lrelu16v(h1);

    v2f h2[16];
#pragma unroll
    for (int k = 0; k < 16; k++) h2[k] = B2v[k];
    densevv<32>(W2, h1, h2);
    lrelu16v(h2);

#pragma unroll
    for (int k = 0; k < 16; k++) o[k] = B3v[k];
    densevv<32>(W3, h2, o);
}

// Packed in-place reduce-scatter butterfly over v2f[16] = 32 channels.
// DESTROYS v. lane L<32 -> sum of channel L; lane L>=32 -> sumsq of ch L-32.
// Same algorithm proven correct in R2/R3/R4 runs.
__device__ __forceinline__ float stats_reduce64v(v2f* vv, int lane) {
    const bool hi = lane >= 32;
#pragma unroll
    for (int j = 0; j < 32; j++) {
        float s = vv[j >> 1][j & 1], q = s * s;
        float r = __shfl_xor(hi ? s : q, 32, 64);
        vv[j >> 1][j & 1] = (hi ? q : s) + r;
    }
#pragma unroll
    for (int m = 16; m >= 1; m >>= 1) {
        const bool b = (lane & m) != 0;
#pragma unroll
        for (int j = 0; j < m; j++) {
            float a = vv[j >> 1][j & 1], c = vv[(j + m) >> 1][(j + m) & 1];
            float r = __shfl_xor(b ? a : c, m, 64);
            vv[j >> 1][j & 1] = (b ? c : a) + r;
        }
    }
    return vv[0][0];
}

// ---------------- prep: dtype detect + fp32 weight conversion ----------------
__global__ void prep_kernel(
    const uint* __restrict__ x,
    const void* __restrict__ eW1, const void* __restrict__ eb1,
    const void* __restrict__ eW2, const void* __restrict__ eb2,
    const void* __restrict__ eW3, const void* __restrict__ eb3,
    const void* __restrict__ nW1, const void* __restrict__ nb1,
    const void* __restrict__ nW2, const void* __restrict__ nb2,
    const void* __restrict__ nW3, const void* __restrict__ nb3,
    int* __restrict__ flag, float* __restrict__ wts)
{
    __shared__ int cnt;
    const int tid = threadIdx.x;
    if (tid == 0) cnt = 0;
    __syncthreads();
    if (tid < 64) {
        uint w = x[tid];
        uint e = (w >> 7) & 0xFFu;
        if (e >= 110u && e <= 134u) atomicAdd(&cnt, 1);
    }
    __syncthreads();
    const bool f32 = (cnt < 32);
    if (tid == 0) flag[0] = f32 ? 1 : 0;
    auto rd = [&](const void* p, int i) -> float {
        return f32 ? ((const float*)p)[i] : bf2f(((const uint16_t*)p)[i]);
    };
    for (int i = tid; i < 1056; i += 256) wts[W_EW1 + i] = rd(eW1, i);
    for (int i = tid; i < 1024; i += 256) {
        wts[W_EW2 + i] = rd(eW2, i); wts[W_EW3 + i] = rd(eW3, i);
        wts[W_NW1 + i] = rd(nW1, i); wts[W_NW2 + i] = rd(nW2, i); wts[W_NW3 + i] = rd(nW3, i);
    }
    if (tid < 32) {
        wts[W_EB1 + tid] = rd(eb1, tid); wts[W_EB2 + tid] = rd(eb2, tid); wts[W_EB3 + tid] = rd(eb3, tid);
        wts[W_NB1 + tid] = rd(nb1, tid); wts[W_NB2 + tid] = rd(nb2, tid); wts[W_NB3 + tid] = rd(nb3, tid);
    }
}

// ------- pass 1: ONE edge branch per block (blockIdx.y: 0 inpl, 1 fwd, 2 bwd) -------
// Light per-thread live set (~80 VGPR) -> no spill, good natural occupancy.
template <bool F32, bool STORE>
__global__ void edge_branch_kernel(
    const void* __restrict__ x, const float* __restrict__ wts,
    const int* __restrict__ flag, float* __restrict__ gstats /*192*/,
    float* __restrict__ eout)
{
    if ((flag[0] != 0) != F32) return;
    __shared__ float sSt[64];
    const int tid = threadIdx.x;
    const int lane = tid & 63;
    const int by = blockIdx.y;
    if (tid < 64) sSt[tid] = 0.f;
    __syncthreads();

    const uint r = blockIdx.x * 256u + (uint)tid;
    const uint t = r & 511u;
    const float dir = (by == 1) ? 1.f : (by == 2) ? -1.f : 0.f;
    const bool valid = (by == 0) || ((by == 1) ? (t > 0u) : (t < 511u));
    const uint rn = (by == 1 && t > 0u) ? r - 1u
                  : (by == 2 && t < 511u) ? r + 1u : r;

    float xt[16]; loadrow16<F32>(x, (size_t)r << 4, xt);
    float xn[16]; loadrow16<F32>(x, (size_t)rn << 4, xn);

    v2f o[16];
    edge_mlp_v2f<F32>(wts, xt, xn, dir, o);

    if (STORE) {
        float4* q = (float4*)(eout + (size_t)by * EOUT_BR_STRIDE + (size_t)r * 32u);
#pragma unroll
        for (int k = 0; k < 8; k++)
            q[k] = make_float4(o[2*k][0], o[2*k][1], o[2*k+1][0], o[2*k+1][1]);
    }
    const float vf = valid ? 1.f : 0.f;
#pragma unroll
    for (int k = 0; k < 16; k++) o[k] *= vf;
    atomicAdd(&sSt[lane], stats_reduce64v(o, lane));
    __syncthreads();
    if (tid < 64) atomicAdd(&gstats[by * 64 + tid], sSt[tid]);
}

// ------------- tiny: edge BN affine coefficients -> workspace (SGPR path) -------------
template <bool F32>
__global__ void edge_affine_kernel(
    const float* __restrict__ gstats_edge,
    const void* __restrict__ egamma, const void* __restrict__ ebeta,
    const int* __restrict__ flag, float* __restrict__ wts_aff)
{
    if ((flag[0] != 0) != F32) return;
    const int tid = threadIdx.x;
    if (tid < 32) {
        float g = wv<F32>(egamma, tid), be = wv<F32>(ebeta, tid);
#pragma unroll
        for (int br = 0; br < 3; br++) {
            float cnt = (br == 0) ? (float)NT : (float)NTM;
            float s = gstats_edge[br * 64 + tid], q = gstats_edge[br * 64 + 32 + tid];
            float mu = s / cnt;
            float var = q / cnt - mu * mu;
            float sc = g * rsqrtf(var + BN_EPS);
            wts_aff[W_AFF + br * 64 + tid] = sc;
            wts_aff[W_AFF + br * 64 + 32 + tid] = be - mu * sc;
        }
    }
}

// shared node-MLP tail: agg -> g3 (v2f), store + stats
template <bool F32>
__device__ __forceinline__ void node_tail(
    const float* __restrict__ wts, v2f* agg, uint r,
    void* __restrict__ out, float* __restrict__ sSt, int lane)
{
    const float* __restrict__ NW1 = wts + W_NW1;
    const float* __restrict__ NW2 = wts + W_NW2;
    const float* __restrict__ NW3 = wts + W_NW3;
    const v2f* __restrict__ NB1v = (const v2f*)(wts + W_NB1);
    const v2f* __restrict__ NB2v = (const v2f*)(wts + W_NB2);
    const v2f* __restrict__ NB3v = (const v2f*)(wts + W_NB3);

    v2f g1[16];
#pragma unroll
    for (int k = 0; k < 16; k++) g1[k] = NB1v[k];
    densevv<32>(NW1, agg, g1);
    lrelu16v(g1);
    v2f g2[16];
#pragma unroll
    for (int k = 0; k < 16; k++) g2[k] = NB2v[k];
    densevv<32>(NW2, g1, g2);
    lrelu16v(g2);
    v2f g3[16];
#pragma unroll
    for (int k = 0; k < 16; k++) g3[k] = NB3v[k];
    densevv<32>(NW3, g2, g3);

    float gf[32];
#pragma unroll
    for (int k = 0; k < 16; k++) { gf[2*k] = g3[k][0]; gf[2*k+1] = g3[k][1]; }
    storerow32<F32>(out, (size_t)r * 32u, gf);
    atomicAdd(&sSt[lane], stats_reduce64v(g3, lane));
}

// -------- pass 2 (stored): load branch outputs, affine, node MLP --------
template <bool F32>
__global__ void node_store_kernel(
    const float* __restrict__ eout, const float* __restrict__ wts,
    const int* __restrict__ flag, float* __restrict__ gstats_node,
    void* __restrict__ out)
{
    if ((flag[0] != 0) != F32) return;
    __shared__ float sSt[64];
    const int tid = threadIdx.x;
    const int lane = tid & 63;
    if (tid < 64) sSt[tid] = 0.f;
    __syncthreads();

    const float* __restrict__ AFF = wts + W_AFF;
    const uint r = blockIdx.x * 256u + (uint)tid;
    const uint t = r & 511u;
    const float vf0 = (t > 0u) ? 1.f : 0.f;
    const float vf1 = (t < 511u) ? 1.f : 0.f;

    float ob[32];
    v2f agg[16];
    loadrow32<true>((const void*)eout, (size_t)r * 32u, ob);
    {
        const v2f* SC = (const v2f*)(AFF);
        const v2f* SH = (const v2f*)(AFF + 32);
#pragma unroll
        for (int k = 0; k < 16; k++) {
            v2f ov; ov[0] = ob[2*k]; ov[1] = ob[2*k+1];
            agg[k] = SC[k] * ov + SH[k];
        }
    }
    loadrow32<true>((const void*)eout, EOUT_BR_STRIDE + (size_t)r * 32u, ob);
    {
        const v2f* SC = (const v2f*)(AFF + 64);
        const v2f* SH = (const v2f*)(AFF + 96);
#pragma unroll
        for (int k = 0; k < 16; k++) {
            v2f ov; ov[0] = ob[2*k]; ov[1] = ob[2*k+1];
            agg[k] += (SC[k] * ov + SH[k]) * vf0;
        }
    }
    loadrow32<true>((const void*)eout, 2u * EOUT_BR_STRIDE + (size_t)r * 32u, ob);
    {
        const v2f* SC = (const v2f*)(AFF + 128);
        const v2f* SH = (const v2f*)(AFF + 160);
#pragma unroll
        for (int k = 0; k < 16; k++) {
            v2f ov; ov[0] = ob[2*k]; ov[1] = ob[2*k+1];
            agg[k] += (SC[k] * ov + SH[k]) * vf1;
        }
    }

    node_tail<F32>(wts, agg, r, out, sSt, lane);
    __syncthreads();
    if (tid < 64) atomicAdd(&gstats_node[tid], sSt[tid]);
}

// -------- pass 2 (fallback, ws too small): recompute branches --------
template <bool F32>
__global__ void node_recompute_kernel(
    const void* __restrict__ x, const float* __restrict__ wts,
    const int* __restrict__ flag, float* __restrict__ gstats_node,
    void* __restrict__ out)
{
    if ((flag[0] != 0) != F32) return;
    __shared__ float sSt[64];
    const int tid = threadIdx.x;
    const int lane = tid & 63;
    if (tid < 64) sSt[tid] = 0.f;
    __syncthreads();

    const float* __restrict__ AFF = wts + W_AFF;
    const uint r = blockIdx.x * 256u + (uint)tid;
    const uint t = r & 511u;
    float xt[16]; loadrow16<F32>(x, (size_t)r << 4, xt);
    v2f agg[16], o[16];

    edge_mlp_v2f<F32>(wts, xt, xt, 0.f, o);
    {
        const v2f* SC = (const v2f*)(AFF);
        const v2f* SH = (const v2f*)(AFF + 32);
#pragma unroll
        for (int k = 0; k < 16; k++) agg[k] = SC[k] * o[k] + SH[k];
    }
    {
        const float vf = (t > 0u) ? 1.f : 0.f;
        const uint rn = (t > 0u) ? r - 1u : r;
        float xn[16]; loadrow16<F32>(x, (size_t)rn << 4, xn);
        edge_mlp_v2f<F32>(wts, xt, xn, 1.f, o);
        const v2f* SC = (const v2f*)(AFF + 64);
        const v2f* SH = (const v2f*)(AFF + 96);
#pragma unroll
        for (int k = 0; k < 16; k++) agg[k] += (SC[k] * o[k] + SH[k]) * vf;
    }
    {
        const float vf = (t < 511u) ? 1.f : 0.f;
        const uint rn = (t < 511u) ? r + 1u : r;
        float xn[16]; loadrow16<F32>(x, (size_t)rn << 4, xn);
        edge_mlp_v2f<F32>(wts, xt, xn, -1.f, o);
        const v2f* SC = (const v2f*)(AFF + 128);
        const v2f* SH = (const v2f*)(AFF + 160);
#pragma unroll
        for (int k = 0; k < 16; k++) agg[k] += (SC[k] * o[k] + SH[k]) * vf;
    }

    node_tail<F32>(wts, agg, r, out, sSt, lane);
    __syncthreads();
    if (tid < 64) atomicAdd(&gstats_node[tid], sSt[tid]);
}

// ---------------- pass 3: in-place node BN affine ----------------
template <bool F32>
__global__ void finalize_kernel(
    const float* __restrict__ gstats_node,
    const void* __restrict__ ngamma, const void* __restrict__ nbeta,
    const int* __restrict__ flag, void* __restrict__ out)
{
    if ((flag[0] != 0) != F32) return;
    __shared__ float sc[32], sh[32];
    const int tid = threadIdx.x;
    if (tid < 32) {
        float s = gstats_node[tid], q = gstats_node[32 + tid];
        float mu = s / (float)NT;
        float var = q / (float)NT - mu * mu;
        float k = wv<F32>(ngamma, tid) * rsqrtf(var + BN_EPS);
        sc[tid] = k; sh[tid] = wv<F32>(nbeta, tid) - mu * k;
    }
    __syncthreads();
    const uint r = blockIdx.x * 256u + (uint)tid;
    float v[32]; loadrow32<F32>(out, (size_t)r * 32u, v);
    float o[32];
#pragma unroll
    for (int j = 0; j < 32; j++) o[j] = fmaf(sc[j], v[j], sh[j]);
    storerow32<F32>(out, (size_t)r * 32u, o);
}

extern "C" void kernel_launch(void* const* d_in, const int* in_sizes, int n_in,
                              void* d_out, int out_size, void* d_ws, size_t ws_size,
                              hipStream_t stream) {
    const void* x   = d_in[0];
    const void* eW1 = d_in[1]; const void* eb1 = d_in[2];
    const void* eW2 = d_in[3]; const void* eb2 = d_in[4];
    const void* eW3 = d_in[5]; const void* eb3 = d_in[6];
    const void* eg  = d_in[7]; const void* ebt = d_in[8];
    const void* nW1 = d_in[9]; const void* nb1 = d_in[10];
    const void* nW2 = d_in[11]; const void* nb2 = d_in[12];
    const void* nW3 = d_in[13]; const void* nb3 = d_in[14];
    const void* ng  = d_in[15]; const void* nbt = d_in[16];

    float* wts   = (float*)d_ws;                       // fp32 weights + affine
    float* stats = (float*)((char*)d_ws + 32768);      // [0..191] edge, [192..255] node
    int* flag    = (int*)((char*)d_ws + 36864);        // dtype flag: 1 = fp32, 0 = bf16
    float* eout  = (float*)((char*)d_ws + WS_EDGE_BYTE_OFF);

    const size_t need = WS_EDGE_BYTE_OFF + 3ull * (size_t)NT * 32ull * sizeof(float);
    const bool stored = (ws_size >= need);

    hipMemsetAsync((char*)d_ws + 32768, 0, 8192, stream);
    prep_kernel<<<dim3(1), dim3(256), 0, stream>>>((const uint*)x,
        eW1, eb1, eW2, eb2, eW3, eb3, nW1, nb1, nW2, nb2, nW3, nb3, flag, wts);

    dim3 blk(256), grid(NT / 256), egrid(NT / 256, 3);
    if (stored) {
        edge_branch_kernel<true,  true><<<egrid, blk, 0, stream>>>(x, wts, flag, stats, eout);
        edge_branch_kernel<false, true><<<egrid, blk, 0, stream>>>(x, wts, flag, stats, eout);
    } else {
        edge_branch_kernel<true,  false><<<egrid, blk, 0, stream>>>(x, wts, flag, stats, eout);
        edge_branch_kernel<false, false><<<egrid, blk, 0, stream>>>(x, wts, flag, stats, eout);
    }
    edge_affine_kernel<true><<<dim3(1), dim3(64), 0, stream>>>(stats, eg, ebt, flag, wts);
    edge_affine_kernel<false><<<dim3(1), dim3(64), 0, stream>>>(stats, eg, ebt, flag, wts);
    if (stored) {
        node_store_kernel<true><<<grid, blk, 0, stream>>>(eout, wts, flag, stats + 192, d_out);
        node_store_kernel<false><<<grid, blk, 0, stream>>>(eout, wts, flag, stats + 192, d_out);
    } else {
        node_recompute_kernel<true><<<grid, blk, 0, stream>>>(x, wts, flag, stats + 192, d_out);
        node_recompute_kernel<false><<<grid, blk, 0, stream>>>(x, wts, flag, stats + 192, d_out);
    }
    finalize_kernel<true><<<grid, blk, 0, stream>>>(stats + 192, ng, nbt, flag, d_out);
    finalize_kernel<false><<<grid, blk, 0, stream>>>(stats + 192, ng, nbt, flag, d_out);
}